// Round 10
// baseline (167.442 us; speedup 1.0000x reference)
//
#include <hip/hip_runtime.h>
#include <math.h>

#ifndef M_PI
#define M_PI 3.14159265358979323846
#endif

#define B_ 8
#define S_ 197
#define E_ 384
#define H_ 6
#define D_ 64
#define N_ (B_*S_)          // 1576
#define EN ((size_t)E_*N_)  // 605184
#define NBLK_N 7            // ceil(1576/256)
#define NBLK_CO 64          // 384/6 co-groups
#define NBLK_ADD (NBLK_N*NBLK_CO)  // 448 blocks per projection
#define NBLK_LN 591         // EN/1024

// ---------------------------------------------------------------------------
// Kernel 1: adder 1x1, scalar-W / vector-X.  No LDS tiles, no split-K.
// Thread owns one n column x 6 co rows; W[co][ci] is wave-uniform (SGPR),
// x[ci][n] lane-coalesced and L2-resident.  4-buffer register prefetch
// (32 ci in flight, ~576 VALU-cyc lead).  grid (7, 64, 3) block 256.
// Y[p][co][n] = -sum_ci |x[ci][n]-w[co][ci]| written directly + LN partials.
// ---------------------------------------------------------------------------
__global__ __launch_bounds__(256) void k_adder(
    const float* __restrict__ x,
    const float* __restrict__ wq, const float* __restrict__ wk,
    const float* __restrict__ wv,
    float* __restrict__ Y, float* __restrict__ partials)
{
  const int p = blockIdx.z;
  const float* __restrict__ w = (p == 0) ? wq : (p == 1) ? wk : wv;
  const int co0 = blockIdx.y * 6;
  const int n = blockIdx.x * 256 + threadIdx.x;
  const bool nok = (n < N_);
  const int nc = nok ? n : 0;

  const float* __restrict__ xp = x + nc;
  const float* __restrict__ wp = w + (size_t)co0 * E_;

  float acc[6];
  #pragma unroll
  for (int r = 0; r < 6; ++r) acc[r] = 0.f;

  float xb0[8], xb1[8], xb2[8], xb3[8];
  #pragma unroll
  for (int k = 0; k < 8; ++k) {
    xb0[k] = xp[(size_t)(k +  0) * N_];
    xb1[k] = xp[(size_t)(k +  8) * N_];
    xb2[k] = xp[(size_t)(k + 16) * N_];
    xb3[k] = xp[(size_t)(k + 24) * N_];
  }

  #pragma unroll 1
  for (int c0 = 0; c0 < E_; c0 += 32) {
    const bool more = (c0 + 32) < E_;
    // phase 0: consume xb0 (ci c0..c0+7), then prefetch xb0 <- c0+32..39
    #pragma unroll
    for (int r = 0; r < 6; ++r) {
      const float* wr = wp + (size_t)r * E_ + c0;
      #pragma unroll
      for (int k = 0; k < 8; ++k) acc[r] += fabsf(xb0[k] - wr[k]);
    }
    if (more) {
      #pragma unroll
      for (int k = 0; k < 8; ++k) xb0[k] = xp[(size_t)(c0 + 32 + k) * N_];
    }
    // phase 1
    #pragma unroll
    for (int r = 0; r < 6; ++r) {
      const float* wr = wp + (size_t)r * E_ + c0 + 8;
      #pragma unroll
      for (int k = 0; k < 8; ++k) acc[r] += fabsf(xb1[k] - wr[k]);
    }
    if (more) {
      #pragma unroll
      for (int k = 0; k < 8; ++k) xb1[k] = xp[(size_t)(c0 + 40 + k) * N_];
    }
    // phase 2
    #pragma unroll
    for (int r = 0; r < 6; ++r) {
      const float* wr = wp + (size_t)r * E_ + c0 + 16;
      #pragma unroll
      for (int k = 0; k < 8; ++k) acc[r] += fabsf(xb2[k] - wr[k]);
    }
    if (more) {
      #pragma unroll
      for (int k = 0; k < 8; ++k) xb2[k] = xp[(size_t)(c0 + 48 + k) * N_];
    }
    // phase 3
    #pragma unroll
    for (int r = 0; r < 6; ++r) {
      const float* wr = wp + (size_t)r * E_ + c0 + 24;
      #pragma unroll
      for (int k = 0; k < 8; ++k) acc[r] += fabsf(xb3[k] - wr[k]);
    }
    if (more) {
      #pragma unroll
      for (int k = 0; k < 8; ++k) xb3[k] = xp[(size_t)(c0 + 56 + k) * N_];
    }
  }

  float* Yp = Y + (size_t)p * EN;
  if (nok) {
    #pragma unroll
    for (int r = 0; r < 6; ++r)
      Yp[(size_t)(co0 + r) * N_ + n] = -acc[r];
  }

  float s1 = 0.f, s2 = 0.f;
  if (nok) {
    #pragma unroll
    for (int r = 0; r < 6; ++r) {
      s1 += -acc[r];
      s2 += acc[r] * acc[r];
    }
  }
  #pragma unroll
  for (int off = 32; off > 0; off >>= 1) {
    s1 += __shfl_down(s1, off);
    s2 += __shfl_down(s2, off);
  }
  __shared__ float red[8];
  const int tid = threadIdx.x;
  int wid = tid >> 6, lane = tid & 63;
  if (lane == 0) { red[wid * 2] = s1; red[wid * 2 + 1] = s2; }
  __syncthreads();
  if (tid == 0) {
    float t1 = red[0] + red[2] + red[4] + red[6];
    float t2 = red[1] + red[3] + red[5] + red[7];
    int blk = blockIdx.y * NBLK_N + blockIdx.x;
    partials[((size_t)p * NBLK_ADD + blk) * 2 + 0] = t1;
    partials[((size_t)p * NBLK_ADD + blk) * 2 + 1] = t2;
  }
}

// ---------------------------------------------------------------------------
// Kernel 2: reduce partials -> (mean, rstd) per projection.  grid(3) block 256
// ---------------------------------------------------------------------------
__global__ __launch_bounds__(256) void k_stats(
    const float* __restrict__ partials, float* __restrict__ stats)
{
  const int p = blockIdx.x;
  const int tid = threadIdx.x;
  float s1 = 0.f, s2 = 0.f;
  for (int i = tid; i < NBLK_ADD; i += 256) {
    s1 += partials[((size_t)p * NBLK_ADD + i) * 2 + 0];
    s2 += partials[((size_t)p * NBLK_ADD + i) * 2 + 1];
  }
  #pragma unroll
  for (int off = 32; off > 0; off >>= 1) {
    s1 += __shfl_down(s1, off);
    s2 += __shfl_down(s2, off);
  }
  __shared__ float red[8];
  int wid = tid >> 6, lane = tid & 63;
  if (lane == 0) { red[wid * 2] = s1; red[wid * 2 + 1] = s2; }
  __syncthreads();
  if (tid == 0) {
    float S1 = red[0] + red[2] + red[4] + red[6];
    float S2 = red[1] + red[3] + red[5] + red[7];
    float mean = S1 / (float)EN;
    float var = S2 / (float)EN - mean * mean;
    stats[p * 2 + 0] = mean;
    stats[p * 2 + 1] = rsqrtf(var + 1e-5f);
  }
}

// ---------------------------------------------------------------------------
// Kernel 3: apply LN-all elementwise.  Y slot p -> Z slot p.
// grid (591, 3) block 256, float4 per thread.
// ---------------------------------------------------------------------------
__global__ __launch_bounds__(256) void k_lnall(
    const float* __restrict__ Y, float* __restrict__ Z,
    const float* __restrict__ stats,
    const float* __restrict__ w0, const float* __restrict__ b0,
    const float* __restrict__ w1, const float* __restrict__ b1,
    const float* __restrict__ w2, const float* __restrict__ b2)
{
  const int p = blockIdx.y;
  const float* __restrict__ w = (p == 0) ? w0 : (p == 1) ? w1 : w2;
  const float* __restrict__ b = (p == 0) ? b0 : (p == 1) ? b1 : b2;
  const float mean = stats[p * 2 + 0];
  const float rstd = stats[p * 2 + 1];
  size_t i = ((size_t)blockIdx.x * 256 + threadIdx.x) * 4;
  const float* Yp = Y + (size_t)p * EN;
  float* Zp = Z + (size_t)p * EN;
  float4 y = *(const float4*)(Yp + i);
  float4 wv = *(const float4*)(w + i);
  float4 bv = *(const float4*)(b + i);
  float4 zv;
  zv.x = (y.x - mean) * rstd * wv.x + bv.x;
  zv.y = (y.y - mean) * rstd * wv.y + bv.y;
  zv.z = (y.z - mean) * rstd * wv.z + bv.z;
  zv.w = (y.w - mean) * rstd * wv.w + bv.w;
  *(float4*)(Zp + i) = zv;
}

// ---------------------------------------------------------------------------
// Kernel 4: fused attention, 16 Q-rows per block (1 row/thread-group-row).
// grid (48, 13) block 256.  O += V[s] folds the +eye(S).
// ---------------------------------------------------------------------------
__global__ __launch_bounds__(256) void k_attn(
    const float* __restrict__ zq, const float* __restrict__ zk,
    const float* __restrict__ zv, float* __restrict__ obuf, float scale)
{
  const int bh = blockIdx.x, b = bh / H_, h = bh % H_;
  const int s0 = blockIdx.y * 16;

  __shared__ float Qs[16][68];    // [row][d]
  __shared__ float KVs[64][68];   // K phase: [d][t_local]; V phase: [t_local][d]
  __shared__ float Ps[16][200];   // unnormalized exp scores
  __shared__ float linv[16];

  const int tid = threadIdx.x;
  const int tx = tid & 15;        // t-slice (4 t) / d-slice (4 d)
  const int ty = tid >> 4;        // row 0..15

  // stage Q: 16 rows x 64 d, one float4 per thread, direct [row][d]
  {
    int sl = tid >> 4, c4 = (tid & 15) * 4;
    int s = s0 + sl;
    float4 v = make_float4(0.f, 0.f, 0.f, 0.f);
    if (s < S_) v = *(const float4*)(zq + (size_t)(b * S_ + s) * E_ + h * D_ + c4);
    *(float4*)(&Qs[sl][c4]) = v;
  }

  float accS[4][4];
  #pragma unroll
  for (int tt = 0; tt < 4; ++tt)
    #pragma unroll
    for (int j = 0; j < 4; ++j) accS[tt][j] = 0.f;

  // ---- QK^T: KVs = K tile [d][t] ----
  #pragma unroll
  for (int tt = 0; tt < 4; ++tt) {
    __syncthreads();   // prior consumers done (covers Qs staging at tt=0)
    #pragma unroll
    for (int it = 0; it < 4; ++it) {
      int idx = tid + it * 256;
      int tl = idx >> 4, c4 = (idx & 15) * 4;
      int t = tt * 64 + tl;
      float4 u = make_float4(0.f, 0.f, 0.f, 0.f);
      if (t < S_) u = *(const float4*)(zk + (size_t)(b * S_ + t) * E_ + h * D_ + c4);
      KVs[c4 + 0][tl] = u.x; KVs[c4 + 1][tl] = u.y;
      KVs[c4 + 2][tl] = u.z; KVs[c4 + 3][tl] = u.w;
    }
    __syncthreads();
    #pragma unroll 4
    for (int dd = 0; dd < 16; ++dd) {
      float4 q4 = *(const float4*)(&Qs[ty][dd * 4]);
      float qa[4] = {q4.x, q4.y, q4.z, q4.w};
      #pragma unroll
      for (int k = 0; k < 4; ++k) {
        float4 k4 = *(const float4*)(&KVs[dd * 4 + k][tx * 4]);
        accS[tt][0] += qa[k] * k4.x;
        accS[tt][1] += qa[k] * k4.y;
        accS[tt][2] += qa[k] * k4.z;
        accS[tt][3] += qa[k] * k4.w;
      }
    }
  }

  // ---- row softmax (row = ty, cols spread over 16 tx lanes) ----
  float m = -1e30f;
  #pragma unroll
  for (int tt = 0; tt < 4; ++tt)
    #pragma unroll
    for (int j = 0; j < 4; ++j) {
      int t = tt * 64 + tx * 4 + j;
      float v = (t < S_) ? accS[tt][j] * scale : -1e30f;
      accS[tt][j] = v;
      m = fmaxf(m, v);
    }
  #pragma unroll
  for (int off = 1; off < 16; off <<= 1) m = fmaxf(m, __shfl_xor(m, off));
  float sum = 0.f;
  #pragma unroll
  for (int tt = 0; tt < 4; ++tt)
    #pragma unroll
    for (int j = 0; j < 4; ++j) {
      float pv = __expf(accS[tt][j] - m);
      accS[tt][j] = pv;
      sum += pv;
    }
  #pragma unroll
  for (int off = 1; off < 16; off <<= 1) sum += __shfl_xor(sum, off);
  if (tx == 0) linv[ty] = 1.f / sum;
  #pragma unroll
  for (int tt = 0; tt < 4; ++tt) {
    int t4 = tt * 64 + tx * 4;
    if (t4 < 200)
      *(float4*)(&Ps[ty][t4]) =
          make_float4(accS[tt][0], accS[tt][1], accS[tt][2], accS[tt][3]);
  }

  // ---- PV: KVs = V tile [t][d] ----
  float accO[4] = {0.f, 0.f, 0.f, 0.f};
  #pragma unroll
  for (int tt = 0; tt < 4; ++tt) {
    __syncthreads();   // covers Ps/linv visibility at tt=0
    #pragma unroll
    for (int it = 0; it < 4; ++it) {
      int idx = tid + it * 256;
      int tl = idx >> 4, c4 = (idx & 15) * 4;
      int t = tt * 64 + tl;
      float4 u = make_float4(0.f, 0.f, 0.f, 0.f);
      if (t < S_) u = *(const float4*)(zv + (size_t)(b * S_ + t) * E_ + h * D_ + c4);
      *(float4*)(&KVs[tl][c4]) = u;
    }
    __syncthreads();
    const int tmax = (tt < 3) ? 64 : 8;   // Ps cols < 200 (tail zeros)
    #pragma unroll 8
    for (int tl = 0; tl < tmax; ++tl) {
      float pp = Ps[ty][tt * 64 + tl];
      float4 v4 = *(const float4*)(&KVs[tl][tx * 4]);
      accO[0] += pp * v4.x;
      accO[1] += pp * v4.y;
      accO[2] += pp * v4.z;
      accO[3] += pp * v4.w;
    }
  }

  // epilogue: O = O*inv + V[s]  (identity fold)
  const int s = s0 + ty;
  if (s < S_) {
    float inv = linv[ty];
    float4 vs = *(const float4*)(zv + (size_t)(b * S_ + s) * E_ + h * D_ + tx * 4);
    float4 o;
    o.x = accO[0] * inv + vs.x;
    o.y = accO[1] * inv + vs.y;
    o.z = accO[2] * inv + vs.z;
    o.w = accO[3] * inv + vs.w;
    *(float4*)(obuf + (size_t)(b * S_ + s) * E_ + h * D_ + tx * 4) = o;
  }
}

// ---------------------------------------------------------------------------
// Kernel 5: LayerNorm over last dim (E) per token row. grid(394) block 256.
// ---------------------------------------------------------------------------
__global__ __launch_bounds__(256) void k_lnlast(
    const float* __restrict__ obuf,
    const float* __restrict__ lw, const float* __restrict__ lb,
    float* __restrict__ oln)
{
  const int row = blockIdx.x * 4 + (threadIdx.x >> 6);
  const int lane = threadIdx.x & 63;
  const float* base = obuf + (size_t)row * E_;
  float v[6];
  float s1 = 0.f;
  #pragma unroll
  for (int j = 0; j < 6; ++j) { v[j] = base[lane + 64 * j]; s1 += v[j]; }
  #pragma unroll
  for (int off = 32; off > 0; off >>= 1) s1 += __shfl_xor(s1, off);
  float mean = s1 * (1.f / E_);
  float s2 = 0.f;
  #pragma unroll
  for (int j = 0; j < 6; ++j) { float d = v[j] - mean; s2 += d * d; }
  #pragma unroll
  for (int off = 32; off > 0; off >>= 1) s2 += __shfl_xor(s2, off);
  float rstd = rsqrtf(s2 * (1.f / E_) + 1e-5f);
  float* ob = oln + (size_t)row * E_;
  #pragma unroll
  for (int j = 0; j < 6; ++j) {
    int e = lane + 64 * j;
    ob[e] = (v[j] - mean) * rstd * lw[e] + lb[e];
  }
}

// ---------------------------------------------------------------------------
// Kernel 6: final GEMM  out[n][j] = sum_e oln[n][e]*fcw[j][e] + fcb[j]
// Tile 64j x 32n, thread 4j x 2n.  grid (6, 50) block 256.
// ---------------------------------------------------------------------------
__global__ __launch_bounds__(256) void k_fc(
    const float* __restrict__ oln, const float* __restrict__ fcw,
    const float* __restrict__ fcb, float* __restrict__ out)
{
  const int j0 = blockIdx.x * 64, n0 = blockIdx.y * 32;
  __shared__ float Xs[16][36];   // [e][n]
  __shared__ float Ws[16][68];   // [e][j]
  const int tid = threadIdx.x;
  const int tx = tid & 15, ty = tid >> 4;
  float acc[4][2];
  #pragma unroll
  for (int i = 0; i < 4; ++i) { acc[i][0] = 0.f; acc[i][1] = 0.f; }

  for (int e0 = 0; e0 < E_; e0 += 16) {
    {
      int nl = tid >> 3, e2 = (tid & 7) * 2;
      int n = n0 + nl;
      float2 v = make_float2(0.f, 0.f);
      if (n < N_) v = *(const float2*)(oln + (size_t)n * E_ + e0 + e2);
      Xs[e2 + 0][nl] = v.x; Xs[e2 + 1][nl] = v.y;
      int jl = tid >> 2, c4 = (tid & 3) * 4;
      float4 u = *(const float4*)(fcw + (size_t)(j0 + jl) * E_ + e0 + c4);
      Ws[c4 + 0][jl] = u.x; Ws[c4 + 1][jl] = u.y;
      Ws[c4 + 2][jl] = u.z; Ws[c4 + 3][jl] = u.w;
    }
    __syncthreads();
    #pragma unroll
    for (int cc = 0; cc < 16; ++cc) {
      float2 x2 = *(const float2*)(&Xs[cc][tx * 2]);
      float4 w4 = *(const float4*)(&Ws[cc][ty * 4]);
      float xa[2] = {x2.x, x2.y};
      float wa[4] = {w4.x, w4.y, w4.z, w4.w};
      #pragma unroll
      for (int i = 0; i < 4; ++i) {
        acc[i][0] += wa[i] * xa[0];
        acc[i][1] += wa[i] * xa[1];
      }
    }
    __syncthreads();
  }
  const int jc = j0 + ty * 4;
  float4 bv = *(const float4*)(fcb + jc);
  #pragma unroll
  for (int jn = 0; jn < 2; ++jn) {
    int n = n0 + tx * 2 + jn;
    if (n < N_) {
      float4 o;
      o.x = acc[0][jn] + bv.x;
      o.y = acc[1][jn] + bv.y;
      o.z = acc[2][jn] + bv.z;
      o.w = acc[3][jn] + bv.w;
      *(float4*)(out + (size_t)n * E_ + jc) = o;
    }
  }
}

// ---------------------------------------------------------------------------
extern "C" void kernel_launch(void* const* d_in, const int* in_sizes, int n_in,
                              void* d_out, int out_size, void* d_ws, size_t ws_size,
                              hipStream_t stream)
{
  const float* x   = (const float*)d_in[0];
  const float* wq  = (const float*)d_in[1];
  const float* wk  = (const float*)d_in[2];
  const float* wv  = (const float*)d_in[3];
  const float* qw  = (const float*)d_in[4];
  const float* qb  = (const float*)d_in[5];
  const float* kw  = (const float*)d_in[6];
  const float* kb  = (const float*)d_in[7];
  const float* vw  = (const float*)d_in[8];
  const float* vb  = (const float*)d_in[9];
  const float* ow  = (const float*)d_in[10];
  const float* obp = (const float*)d_in[11];
  const float* fcw = (const float*)d_in[12];
  const float* fcb = (const float*)d_in[13];
  float* out = (float*)d_out;
  float* ws  = (float*)d_ws;

  // ws layout (floats): Y = slots 0..2, Z = slots 3..5.
  // After lnall, Y is dead: obuf = slot 0, oln = slot 1.
  float* Y     = ws;
  float* Z     = ws + 3 * EN;
  float* obuf  = ws + 0 * EN;
  float* oln   = ws + 1 * EN;
  float* part  = ws + 6 * EN;                  // 3*448*2
  float* stats = part + 3 * NBLK_ADD * 2;      // 6

  const float scale = (float)pow(2.0 * D_ * (1.0 - 2.0 / M_PI), -0.5);

  k_adder<<<dim3(NBLK_N, NBLK_CO, 3), 256, 0, stream>>>(x, wq, wk, wv, Y, part);
  k_stats<<<dim3(3), 256, 0, stream>>>(part, stats);
  k_lnall<<<dim3(NBLK_LN, 3), 256, 0, stream>>>(Y, Z, stats, qw, qb, kw, kb, vw, vb);
  const float* zq = Z;
  const float* zk = Z + EN;
  const float* zv = Z + 2 * EN;
  k_attn<<<dim3(48, 13), 256, 0, stream>>>(zq, zk, zv, obuf, scale);
  k_lnlast<<<dim3(394), 256, 0, stream>>>(obuf, ow, obp, oln);
  k_fc<<<dim3(6, 50), 256, 0, stream>>>(oln, fcw, fcb, out);
}

// Round 11
// 136.213 us; speedup vs baseline: 1.2293x; 1.2293x over previous
//
#include <hip/hip_runtime.h>
#include <math.h>

#ifndef M_PI
#define M_PI 3.14159265358979323846
#endif

#define B_ 8
#define S_ 197
#define E_ 384
#define H_ 6
#define D_ 64
#define N_ (B_*S_)          // 1576
#define EN ((size_t)E_*N_)  // 605184
#define NBLK_N 4            // ceil(1576/512) n-chunks of 512
#define NBLK_CO 96          // 384/4 co-groups
#define NBLK_ADD (NBLK_N*NBLK_CO)  // 384 blocks per projection
#define NBLK_LN 591         // EN/1024

// ---------------------------------------------------------------------------
// Kernel 1: adder 1x1, W-in-LDS / vector-X hybrid.
// Thread owns 2 consecutive n-columns x 4 co rows.  W rows staged to LDS
// once (6 KB, one barrier), read via uniform ds_read_b128 (broadcast).
// x loads are float2, lane-coalesced 512B/wave, L2-resident; 8-deep
// double-buffered register prefetch (~256-cyc lead, statically indexed).
// Y[p][co][n] = -sum_ci |x[ci][n]-w[co][ci]| written directly + LN partials.
// grid (4, 96, 3) block 256.
// ---------------------------------------------------------------------------
__global__ __launch_bounds__(256) void k_adder(
    const float* __restrict__ x,
    const float* __restrict__ wq, const float* __restrict__ wk,
    const float* __restrict__ wv,
    float* __restrict__ Y, float* __restrict__ partials)
{
  const int p = blockIdx.z;
  const float* __restrict__ w = (p == 0) ? wq : (p == 1) ? wk : wv;
  const int co0 = blockIdx.y * 4;
  const int n = (blockIdx.x * 256 + threadIdx.x) * 2;
  const bool nok = (n + 1) < N_;      // n even, N_ even -> pair valid or not
  const int nc = nok ? n : 0;
  const float* __restrict__ xp = x + nc;

  __shared__ float Ws[4 * E_];        // 6 KB, rows co0..co0+3 contiguous
  __shared__ float red[8];
  {
    const float* wp = w + (size_t)co0 * E_;   // 4*E_ consecutive floats
    #pragma unroll 2
    for (int i = threadIdx.x; i < 4 * E_; i += 256) Ws[i] = wp[i];
  }
  __syncthreads();

  float acc[4][2];
  #pragma unroll
  for (int r = 0; r < 4; ++r) { acc[r][0] = 0.f; acc[r][1] = 0.f; }

  float2 xbA[8], xbB[8];
  #pragma unroll
  for (int k = 0; k < 8; ++k) {
    xbA[k] = *(const float2*)(xp + (size_t)(k + 0) * N_);
    xbB[k] = *(const float2*)(xp + (size_t)(k + 8) * N_);
  }

  #pragma unroll 1
  for (int c0 = 0; c0 < E_; c0 += 16) {
    const bool more = (c0 + 16) < E_;
    // consume A (ci c0..c0+7): W via uniform ds_read_b128
    #pragma unroll
    for (int r = 0; r < 4; ++r) {
      #pragma unroll
      for (int q = 0; q < 2; ++q) {
        float4 wv4 = *(const float4*)(&Ws[r * E_ + c0 + q * 4]);
        float wa[4] = {wv4.x, wv4.y, wv4.z, wv4.w};
        #pragma unroll
        for (int j = 0; j < 4; ++j) {
          acc[r][0] += fabsf(xbA[q * 4 + j].x - wa[j]);
          acc[r][1] += fabsf(xbA[q * 4 + j].y - wa[j]);
        }
      }
    }
    if (more) {
      #pragma unroll
      for (int k = 0; k < 8; ++k)
        xbA[k] = *(const float2*)(xp + (size_t)(c0 + 16 + k) * N_);
    }
    // consume B (ci c0+8..c0+15)
    #pragma unroll
    for (int r = 0; r < 4; ++r) {
      #pragma unroll
      for (int q = 0; q < 2; ++q) {
        float4 wv4 = *(const float4*)(&Ws[r * E_ + c0 + 8 + q * 4]);
        float wa[4] = {wv4.x, wv4.y, wv4.z, wv4.w};
        #pragma unroll
        for (int j = 0; j < 4; ++j) {
          acc[r][0] += fabsf(xbB[q * 4 + j].x - wa[j]);
          acc[r][1] += fabsf(xbB[q * 4 + j].y - wa[j]);
        }
      }
    }
    if (more) {
      #pragma unroll
      for (int k = 0; k < 8; ++k)
        xbB[k] = *(const float2*)(xp + (size_t)(c0 + 24 + k) * N_);
    }
  }

  float* Yp = Y + (size_t)p * EN;
  if (nok) {
    #pragma unroll
    for (int r = 0; r < 4; ++r) {
      float2 yv;
      yv.x = -acc[r][0];
      yv.y = -acc[r][1];
      *(float2*)(Yp + (size_t)(co0 + r) * N_ + n) = yv;
    }
  }

  float s1 = 0.f, s2 = 0.f;
  if (nok) {
    #pragma unroll
    for (int r = 0; r < 4; ++r) {
      s1 += -(acc[r][0] + acc[r][1]);
      s2 += acc[r][0] * acc[r][0] + acc[r][1] * acc[r][1];
    }
  }
  #pragma unroll
  for (int off = 32; off > 0; off >>= 1) {
    s1 += __shfl_down(s1, off);
    s2 += __shfl_down(s2, off);
  }
  const int tid = threadIdx.x;
  int wid = tid >> 6, lane = tid & 63;
  if (lane == 0) { red[wid * 2] = s1; red[wid * 2 + 1] = s2; }
  __syncthreads();
  if (tid == 0) {
    float t1 = red[0] + red[2] + red[4] + red[6];
    float t2 = red[1] + red[3] + red[5] + red[7];
    int blk = blockIdx.y * NBLK_N + blockIdx.x;
    partials[((size_t)p * NBLK_ADD + blk) * 2 + 0] = t1;
    partials[((size_t)p * NBLK_ADD + blk) * 2 + 1] = t2;
  }
}

// ---------------------------------------------------------------------------
// Kernel 2: reduce partials -> (mean, rstd) per projection.  grid(3) block 256
// ---------------------------------------------------------------------------
__global__ __launch_bounds__(256) void k_stats(
    const float* __restrict__ partials, float* __restrict__ stats)
{
  const int p = blockIdx.x;
  const int tid = threadIdx.x;
  float s1 = 0.f, s2 = 0.f;
  for (int i = tid; i < NBLK_ADD; i += 256) {
    s1 += partials[((size_t)p * NBLK_ADD + i) * 2 + 0];
    s2 += partials[((size_t)p * NBLK_ADD + i) * 2 + 1];
  }
  #pragma unroll
  for (int off = 32; off > 0; off >>= 1) {
    s1 += __shfl_down(s1, off);
    s2 += __shfl_down(s2, off);
  }
  __shared__ float red[8];
  int wid = tid >> 6, lane = tid & 63;
  if (lane == 0) { red[wid * 2] = s1; red[wid * 2 + 1] = s2; }
  __syncthreads();
  if (tid == 0) {
    float S1 = red[0] + red[2] + red[4] + red[6];
    float S2 = red[1] + red[3] + red[5] + red[7];
    float mean = S1 / (float)EN;
    float var = S2 / (float)EN - mean * mean;
    stats[p * 2 + 0] = mean;
    stats[p * 2 + 1] = rsqrtf(var + 1e-5f);
  }
}

// ---------------------------------------------------------------------------
// Kernel 3: apply LN-all elementwise.  Y slot p -> Z slot p.
// grid (591, 3) block 256, float4 per thread.
// ---------------------------------------------------------------------------
__global__ __launch_bounds__(256) void k_lnall(
    const float* __restrict__ Y, float* __restrict__ Z,
    const float* __restrict__ stats,
    const float* __restrict__ w0, const float* __restrict__ b0,
    const float* __restrict__ w1, const float* __restrict__ b1,
    const float* __restrict__ w2, const float* __restrict__ b2)
{
  const int p = blockIdx.y;
  const float* __restrict__ w = (p == 0) ? w0 : (p == 1) ? w1 : w2;
  const float* __restrict__ b = (p == 0) ? b0 : (p == 1) ? b1 : b2;
  const float mean = stats[p * 2 + 0];
  const float rstd = stats[p * 2 + 1];
  size_t i = ((size_t)blockIdx.x * 256 + threadIdx.x) * 4;
  const float* Yp = Y + (size_t)p * EN;
  float* Zp = Z + (size_t)p * EN;
  float4 y = *(const float4*)(Yp + i);
  float4 wv = *(const float4*)(w + i);
  float4 bv = *(const float4*)(b + i);
  float4 zv;
  zv.x = (y.x - mean) * rstd * wv.x + bv.x;
  zv.y = (y.y - mean) * rstd * wv.y + bv.y;
  zv.z = (y.z - mean) * rstd * wv.z + bv.z;
  zv.w = (y.w - mean) * rstd * wv.w + bv.w;
  *(float4*)(Zp + i) = zv;
}

// ---------------------------------------------------------------------------
// Kernel 4: fused attention, 16 Q-rows per block (1 row/thread-group-row).
// grid (48, 13) block 256.  O += V[s] folds the +eye(S).
// ---------------------------------------------------------------------------
__global__ __launch_bounds__(256) void k_attn(
    const float* __restrict__ zq, const float* __restrict__ zk,
    const float* __restrict__ zv, float* __restrict__ obuf, float scale)
{
  const int bh = blockIdx.x, b = bh / H_, h = bh % H_;
  const int s0 = blockIdx.y * 16;

  __shared__ float Qs[16][68];    // [row][d]
  __shared__ float KVs[64][68];   // K phase: [d][t_local]; V phase: [t_local][d]
  __shared__ float Ps[16][200];   // unnormalized exp scores
  __shared__ float linv[16];

  const int tid = threadIdx.x;
  const int tx = tid & 15;        // t-slice (4 t) / d-slice (4 d)
  const int ty = tid >> 4;        // row 0..15

  // stage Q: 16 rows x 64 d, one float4 per thread, direct [row][d]
  {
    int sl = tid >> 4, c4 = (tid & 15) * 4;
    int s = s0 + sl;
    float4 v = make_float4(0.f, 0.f, 0.f, 0.f);
    if (s < S_) v = *(const float4*)(zq + (size_t)(b * S_ + s) * E_ + h * D_ + c4);
    *(float4*)(&Qs[sl][c4]) = v;
  }

  float accS[4][4];
  #pragma unroll
  for (int tt = 0; tt < 4; ++tt)
    #pragma unroll
    for (int j = 0; j < 4; ++j) accS[tt][j] = 0.f;

  // ---- QK^T: KVs = K tile [d][t] ----
  #pragma unroll
  for (int tt = 0; tt < 4; ++tt) {
    __syncthreads();   // prior consumers done (covers Qs staging at tt=0)
    #pragma unroll
    for (int it = 0; it < 4; ++it) {
      int idx = tid + it * 256;
      int tl = idx >> 4, c4 = (idx & 15) * 4;
      int t = tt * 64 + tl;
      float4 u = make_float4(0.f, 0.f, 0.f, 0.f);
      if (t < S_) u = *(const float4*)(zk + (size_t)(b * S_ + t) * E_ + h * D_ + c4);
      KVs[c4 + 0][tl] = u.x; KVs[c4 + 1][tl] = u.y;
      KVs[c4 + 2][tl] = u.z; KVs[c4 + 3][tl] = u.w;
    }
    __syncthreads();
    #pragma unroll 4
    for (int dd = 0; dd < 16; ++dd) {
      float4 q4 = *(const float4*)(&Qs[ty][dd * 4]);
      float qa[4] = {q4.x, q4.y, q4.z, q4.w};
      #pragma unroll
      for (int k = 0; k < 4; ++k) {
        float4 k4 = *(const float4*)(&KVs[dd * 4 + k][tx * 4]);
        accS[tt][0] += qa[k] * k4.x;
        accS[tt][1] += qa[k] * k4.y;
        accS[tt][2] += qa[k] * k4.z;
        accS[tt][3] += qa[k] * k4.w;
      }
    }
  }

  // ---- row softmax (row = ty, cols spread over 16 tx lanes) ----
  float m = -1e30f;
  #pragma unroll
  for (int tt = 0; tt < 4; ++tt)
    #pragma unroll
    for (int j = 0; j < 4; ++j) {
      int t = tt * 64 + tx * 4 + j;
      float v = (t < S_) ? accS[tt][j] * scale : -1e30f;
      accS[tt][j] = v;
      m = fmaxf(m, v);
    }
  #pragma unroll
  for (int off = 1; off < 16; off <<= 1) m = fmaxf(m, __shfl_xor(m, off));
  float sum = 0.f;
  #pragma unroll
  for (int tt = 0; tt < 4; ++tt)
    #pragma unroll
    for (int j = 0; j < 4; ++j) {
      float pv = __expf(accS[tt][j] - m);
      accS[tt][j] = pv;
      sum += pv;
    }
  #pragma unroll
  for (int off = 1; off < 16; off <<= 1) sum += __shfl_xor(sum, off);
  if (tx == 0) linv[ty] = 1.f / sum;
  #pragma unroll
  for (int tt = 0; tt < 4; ++tt) {
    int t4 = tt * 64 + tx * 4;
    if (t4 < 200)
      *(float4*)(&Ps[ty][t4]) =
          make_float4(accS[tt][0], accS[tt][1], accS[tt][2], accS[tt][3]);
  }

  // ---- PV: KVs = V tile [t][d] ----
  float accO[4] = {0.f, 0.f, 0.f, 0.f};
  #pragma unroll
  for (int tt = 0; tt < 4; ++tt) {
    __syncthreads();   // covers Ps/linv visibility at tt=0
    #pragma unroll
    for (int it = 0; it < 4; ++it) {
      int idx = tid + it * 256;
      int tl = idx >> 4, c4 = (idx & 15) * 4;
      int t = tt * 64 + tl;
      float4 u = make_float4(0.f, 0.f, 0.f, 0.f);
      if (t < S_) u = *(const float4*)(zv + (size_t)(b * S_ + t) * E_ + h * D_ + c4);
      *(float4*)(&KVs[tl][c4]) = u;
    }
    __syncthreads();
    const int tmax = (tt < 3) ? 64 : 8;   // Ps cols < 200 (tail zeros)
    #pragma unroll 8
    for (int tl = 0; tl < tmax; ++tl) {
      float pp = Ps[ty][tt * 64 + tl];
      float4 v4 = *(const float4*)(&KVs[tl][tx * 4]);
      accO[0] += pp * v4.x;
      accO[1] += pp * v4.y;
      accO[2] += pp * v4.z;
      accO[3] += pp * v4.w;
    }
  }

  // epilogue: O = O*inv + V[s]  (identity fold)
  const int s = s0 + ty;
  if (s < S_) {
    float inv = linv[ty];
    float4 vs = *(const float4*)(zv + (size_t)(b * S_ + s) * E_ + h * D_ + tx * 4);
    float4 o;
    o.x = accO[0] * inv + vs.x;
    o.y = accO[1] * inv + vs.y;
    o.z = accO[2] * inv + vs.z;
    o.w = accO[3] * inv + vs.w;
    *(float4*)(obuf + (size_t)(b * S_ + s) * E_ + h * D_ + tx * 4) = o;
  }
}

// ---------------------------------------------------------------------------
// Kernel 5: LayerNorm over last dim (E) per token row. grid(394) block 256.
// ---------------------------------------------------------------------------
__global__ __launch_bounds__(256) void k_lnlast(
    const float* __restrict__ obuf,
    const float* __restrict__ lw, const float* __restrict__ lb,
    float* __restrict__ oln)
{
  const int row = blockIdx.x * 4 + (threadIdx.x >> 6);
  const int lane = threadIdx.x & 63;
  const float* base = obuf + (size_t)row * E_;
  float v[6];
  float s1 = 0.f;
  #pragma unroll
  for (int j = 0; j < 6; ++j) { v[j] = base[lane + 64 * j]; s1 += v[j]; }
  #pragma unroll
  for (int off = 32; off > 0; off >>= 1) s1 += __shfl_xor(s1, off);
  float mean = s1 * (1.f / E_);
  float s2 = 0.f;
  #pragma unroll
  for (int j = 0; j < 6; ++j) { float d = v[j] - mean; s2 += d * d; }
  #pragma unroll
  for (int off = 32; off > 0; off >>= 1) s2 += __shfl_xor(s2, off);
  float rstd = rsqrtf(s2 * (1.f / E_) + 1e-5f);
  float* ob = oln + (size_t)row * E_;
  #pragma unroll
  for (int j = 0; j < 6; ++j) {
    int e = lane + 64 * j;
    ob[e] = (v[j] - mean) * rstd * lw[e] + lb[e];
  }
}

// ---------------------------------------------------------------------------
// Kernel 6: final GEMM  out[n][j] = sum_e oln[n][e]*fcw[j][e] + fcb[j]
// Tile 64j x 32n, thread 4j x 2n.  grid (6, 50) block 256.
// ---------------------------------------------------------------------------
__global__ __launch_bounds__(256) void k_fc(
    const float* __restrict__ oln, const float* __restrict__ fcw,
    const float* __restrict__ fcb, float* __restrict__ out)
{
  const int j0 = blockIdx.x * 64, n0 = blockIdx.y * 32;
  __shared__ float Xs[16][36];   // [e][n]
  __shared__ float Ws[16][68];   // [e][j]
  const int tid = threadIdx.x;
  const int tx = tid & 15, ty = tid >> 4;
  float acc[4][2];
  #pragma unroll
  for (int i = 0; i < 4; ++i) { acc[i][0] = 0.f; acc[i][1] = 0.f; }

  for (int e0 = 0; e0 < E_; e0 += 16) {
    {
      int nl = tid >> 3, e2 = (tid & 7) * 2;
      int n = n0 + nl;
      float2 v = make_float2(0.f, 0.f);
      if (n < N_) v = *(const float2*)(oln + (size_t)n * E_ + e0 + e2);
      Xs[e2 + 0][nl] = v.x; Xs[e2 + 1][nl] = v.y;
      int jl = tid >> 2, c4 = (tid & 3) * 4;
      float4 u = *(const float4*)(fcw + (size_t)(j0 + jl) * E_ + e0 + c4);
      Ws[c4 + 0][jl] = u.x; Ws[c4 + 1][jl] = u.y;
      Ws[c4 + 2][jl] = u.z; Ws[c4 + 3][jl] = u.w;
    }
    __syncthreads();
    #pragma unroll
    for (int cc = 0; cc < 16; ++cc) {
      float2 x2 = *(const float2*)(&Xs[cc][tx * 2]);
      float4 w4 = *(const float4*)(&Ws[cc][ty * 4]);
      float xa[2] = {x2.x, x2.y};
      float wa[4] = {w4.x, w4.y, w4.z, w4.w};
      #pragma unroll
      for (int i = 0; i < 4; ++i) {
        acc[i][0] += wa[i] * xa[0];
        acc[i][1] += wa[i] * xa[1];
      }
    }
    __syncthreads();
  }
  const int jc = j0 + ty * 4;
  float4 bv = *(const float4*)(fcb + jc);
  #pragma unroll
  for (int jn = 0; jn < 2; ++jn) {
    int n = n0 + tx * 2 + jn;
    if (n < N_) {
      float4 o;
      o.x = acc[0][jn] + bv.x;
      o.y = acc[1][jn] + bv.y;
      o.z = acc[2][jn] + bv.z;
      o.w = acc[3][jn] + bv.w;
      *(float4*)(out + (size_t)n * E_ + jc) = o;
    }
  }
}

// ---------------------------------------------------------------------------
extern "C" void kernel_launch(void* const* d_in, const int* in_sizes, int n_in,
                              void* d_out, int out_size, void* d_ws, size_t ws_size,
                              hipStream_t stream)
{
  const float* x   = (const float*)d_in[0];
  const float* wq  = (const float*)d_in[1];
  const float* wk  = (const float*)d_in[2];
  const float* wv  = (const float*)d_in[3];
  const float* qw  = (const float*)d_in[4];
  const float* qb  = (const float*)d_in[5];
  const float* kw  = (const float*)d_in[6];
  const float* kb  = (const float*)d_in[7];
  const float* vw  = (const float*)d_in[8];
  const float* vb  = (const float*)d_in[9];
  const float* ow  = (const float*)d_in[10];
  const float* obp = (const float*)d_in[11];
  const float* fcw = (const float*)d_in[12];
  const float* fcb = (const float*)d_in[13];
  float* out = (float*)d_out;
  float* ws  = (float*)d_ws;

  // ws layout (floats): Y = slots 0..2, Z = slots 3..5.
  // After lnall, Y is dead: obuf = slot 0, oln = slot 1.
  float* Y     = ws;
  float* Z     = ws + 3 * EN;
  float* obuf  = ws + 0 * EN;
  float* oln   = ws + 1 * EN;
  float* part  = ws + 6 * EN;                  // 3*384*2
  float* stats = part + 3 * NBLK_ADD * 2;      // 6

  const float scale = (float)pow(2.0 * D_ * (1.0 - 2.0 / M_PI), -0.5);

  k_adder<<<dim3(NBLK_N, NBLK_CO, 3), 256, 0, stream>>>(x, wq, wk, wv, Y, part);
  k_stats<<<dim3(3), 256, 0, stream>>>(part, stats);
  k_lnall<<<dim3(NBLK_LN, 3), 256, 0, stream>>>(Y, Z, stats, qw, qb, kw, kb, vw, vb);
  const float* zq = Z;
  const float* zk = Z + EN;
  const float* zv = Z + 2 * EN;
  k_attn<<<dim3(48, 13), 256, 0, stream>>>(zq, zk, zv, obuf, scale);
  k_lnlast<<<dim3(394), 256, 0, stream>>>(obuf, ow, obp, oln);
  k_fc<<<dim3(6, 50), 256, 0, stream>>>(oln, fcw, fcb, out);
}

// Round 12
// 119.448 us; speedup vs baseline: 1.4018x; 1.1404x over previous
//
#include <hip/hip_runtime.h>
#include <math.h>

#ifndef M_PI
#define M_PI 3.14159265358979323846
#endif

#define B_ 8
#define S_ 197
#define E_ 384
#define H_ 6
#define D_ 64
#define N_ (B_*S_)          // 1576
#define EN ((size_t)E_*N_)  // 605184
#define NBLK_N 7            // ceil(1576/256)
#define NBLK_ADD (NBLK_N*48)  // 336 blocks per projection
#define NBLK_LN 591         // EN/1024

// ---------------------------------------------------------------------------
// Kernel 1: adder 1x1, scalar-W / vector-X (R9 structure).  No LDS tiles,
// no barriers in the main loop, no split-K.  Thread owns one n column x 8 co
// rows.  W[co][ci] wave-uniform -> s_loads; x[ci][n] lane-coalesced,
// L2-resident.  NEW: Y written with __builtin_nontemporal_store so the
// write stream does not evict X from the per-XCD L2 (R9 showed 21.6 MB
// FETCH = X re-fetched ~9x; the ~900-cyc misses capped VALU issue at 34%).
// grid (7, 48, 3) block 256.
// ---------------------------------------------------------------------------
__global__ __launch_bounds__(256) void k_adder(
    const float* __restrict__ x,
    const float* __restrict__ wq, const float* __restrict__ wk,
    const float* __restrict__ wv,
    float* __restrict__ Y, float* __restrict__ partials)
{
  const int p = blockIdx.z;
  const float* __restrict__ w = (p == 0) ? wq : (p == 1) ? wk : wv;
  const int co0 = blockIdx.y * 8;
  const int n = blockIdx.x * 256 + threadIdx.x;
  const bool nok = (n < N_);
  const int nc = nok ? n : 0;

  const float* __restrict__ xp = x + nc;
  const float* __restrict__ wp = w + (size_t)co0 * E_;

  float acc[8];
  #pragma unroll
  for (int r = 0; r < 8; ++r) acc[r] = 0.f;

  float xbA[8], xbB[8];
  #pragma unroll
  for (int k = 0; k < 8; ++k) xbA[k] = xp[(size_t)k * N_];

  #pragma unroll 1
  for (int c0 = 0; c0 < E_; c0 += 16) {
    // prefetch sub-chunk B (c0+8..c0+15)
    #pragma unroll
    for (int k = 0; k < 8; ++k) xbB[k] = xp[(size_t)(c0 + 8 + k) * N_];
    // consume sub-chunk A
    #pragma unroll
    for (int r = 0; r < 8; ++r) {
      const float* wr = wp + (size_t)r * E_ + c0;
      #pragma unroll
      for (int k = 0; k < 8; ++k)
        acc[r] += fabsf(xbA[k] - wr[k]);
    }
    // prefetch next iteration's sub-chunk A (c0+16..c0+23)
    if (c0 + 16 < E_) {
      #pragma unroll
      for (int k = 0; k < 8; ++k) xbA[k] = xp[(size_t)(c0 + 16 + k) * N_];
    }
    // consume sub-chunk B
    #pragma unroll
    for (int r = 0; r < 8; ++r) {
      const float* wr = wp + (size_t)r * E_ + c0 + 8;
      #pragma unroll
      for (int k = 0; k < 8; ++k)
        acc[r] += fabsf(xbB[k] - wr[k]);
    }
  }

  // store Y = -acc  (coalesced per co row, NON-TEMPORAL: keep X in L2)
  float* Yp = Y + (size_t)p * EN;
  if (nok) {
    #pragma unroll
    for (int r = 0; r < 8; ++r)
      __builtin_nontemporal_store(-acc[r], Yp + (size_t)(co0 + r) * N_ + n);
  }

  // per-block (sum, sumsq) partials for LN-all stats
  float s1 = 0.f, s2 = 0.f;
  if (nok) {
    #pragma unroll
    for (int r = 0; r < 8; ++r) {
      s1 += -acc[r];
      s2 += acc[r] * acc[r];
    }
  }
  #pragma unroll
  for (int off = 32; off > 0; off >>= 1) {
    s1 += __shfl_down(s1, off);
    s2 += __shfl_down(s2, off);
  }
  __shared__ float red[8];
  const int tid = threadIdx.x;
  int wid = tid >> 6, lane = tid & 63;
  if (lane == 0) { red[wid * 2] = s1; red[wid * 2 + 1] = s2; }
  __syncthreads();
  if (tid == 0) {
    float t1 = red[0] + red[2] + red[4] + red[6];
    float t2 = red[1] + red[3] + red[5] + red[7];
    int blk = blockIdx.y * NBLK_N + blockIdx.x;
    partials[((size_t)p * NBLK_ADD + blk) * 2 + 0] = t1;
    partials[((size_t)p * NBLK_ADD + blk) * 2 + 1] = t2;
  }
}

// ---------------------------------------------------------------------------
// Kernel 2: reduce partials -> (mean, rstd) per projection.  grid(3) block 256
// ---------------------------------------------------------------------------
__global__ __launch_bounds__(256) void k_stats(
    const float* __restrict__ partials, float* __restrict__ stats)
{
  const int p = blockIdx.x;
  const int tid = threadIdx.x;
  float s1 = 0.f, s2 = 0.f;
  for (int i = tid; i < NBLK_ADD; i += 256) {
    s1 += partials[((size_t)p * NBLK_ADD + i) * 2 + 0];
    s2 += partials[((size_t)p * NBLK_ADD + i) * 2 + 1];
  }
  #pragma unroll
  for (int off = 32; off > 0; off >>= 1) {
    s1 += __shfl_down(s1, off);
    s2 += __shfl_down(s2, off);
  }
  __shared__ float red[8];
  int wid = tid >> 6, lane = tid & 63;
  if (lane == 0) { red[wid * 2] = s1; red[wid * 2 + 1] = s2; }
  __syncthreads();
  if (tid == 0) {
    float S1 = red[0] + red[2] + red[4] + red[6];
    float S2 = red[1] + red[3] + red[5] + red[7];
    float mean = S1 / (float)EN;
    float var = S2 / (float)EN - mean * mean;
    stats[p * 2 + 0] = mean;
    stats[p * 2 + 1] = rsqrtf(var + 1e-5f);
  }
}

// ---------------------------------------------------------------------------
// Kernel 3: apply LN-all elementwise.  Y slot p -> Z slot p.
// grid (591, 3) block 256, float4 per thread.
// ---------------------------------------------------------------------------
__global__ __launch_bounds__(256) void k_lnall(
    const float* __restrict__ Y, float* __restrict__ Z,
    const float* __restrict__ stats,
    const float* __restrict__ w0, const float* __restrict__ b0,
    const float* __restrict__ w1, const float* __restrict__ b1,
    const float* __restrict__ w2, const float* __restrict__ b2)
{
  const int p = blockIdx.y;
  const float* __restrict__ w = (p == 0) ? w0 : (p == 1) ? w1 : w2;
  const float* __restrict__ b = (p == 0) ? b0 : (p == 1) ? b1 : b2;
  const float mean = stats[p * 2 + 0];
  const float rstd = stats[p * 2 + 1];
  size_t i = ((size_t)blockIdx.x * 256 + threadIdx.x) * 4;
  const float* Yp = Y + (size_t)p * EN;
  float* Zp = Z + (size_t)p * EN;
  float4 y = *(const float4*)(Yp + i);
  float4 wv = *(const float4*)(w + i);
  float4 bv = *(const float4*)(b + i);
  float4 zv;
  zv.x = (y.x - mean) * rstd * wv.x + bv.x;
  zv.y = (y.y - mean) * rstd * wv.y + bv.y;
  zv.z = (y.z - mean) * rstd * wv.z + bv.z;
  zv.w = (y.w - mean) * rstd * wv.w + bv.w;
  *(float4*)(Zp + i) = zv;
}

// ---------------------------------------------------------------------------
// Kernel 4: fused attention, 16 Q-rows per block (1 row/thread-group-row).
// grid (48, 13) block 256.  O += V[s] folds the +eye(S).
// ---------------------------------------------------------------------------
__global__ __launch_bounds__(256) void k_attn(
    const float* __restrict__ zq, const float* __restrict__ zk,
    const float* __restrict__ zv, float* __restrict__ obuf, float scale)
{
  const int bh = blockIdx.x, b = bh / H_, h = bh % H_;
  const int s0 = blockIdx.y * 16;

  __shared__ float Qs[16][68];    // [row][d]
  __shared__ float KVs[64][68];   // K phase: [d][t_local]; V phase: [t_local][d]
  __shared__ float Ps[16][200];   // unnormalized exp scores
  __shared__ float linv[16];

  const int tid = threadIdx.x;
  const int tx = tid & 15;        // t-slice (4 t) / d-slice (4 d)
  const int ty = tid >> 4;        // row 0..15

  // stage Q: 16 rows x 64 d, one float4 per thread, direct [row][d]
  {
    int sl = tid >> 4, c4 = (tid & 15) * 4;
    int s = s0 + sl;
    float4 v = make_float4(0.f, 0.f, 0.f, 0.f);
    if (s < S_) v = *(const float4*)(zq + (size_t)(b * S_ + s) * E_ + h * D_ + c4);
    *(float4*)(&Qs[sl][c4]) = v;
  }

  float accS[4][4];
  #pragma unroll
  for (int tt = 0; tt < 4; ++tt)
    #pragma unroll
    for (int j = 0; j < 4; ++j) accS[tt][j] = 0.f;

  // ---- QK^T: KVs = K tile [d][t] ----
  #pragma unroll
  for (int tt = 0; tt < 4; ++tt) {
    __syncthreads();   // prior consumers done (covers Qs staging at tt=0)
    #pragma unroll
    for (int it = 0; it < 4; ++it) {
      int idx = tid + it * 256;
      int tl = idx >> 4, c4 = (idx & 15) * 4;
      int t = tt * 64 + tl;
      float4 u = make_float4(0.f, 0.f, 0.f, 0.f);
      if (t < S_) u = *(const float4*)(zk + (size_t)(b * S_ + t) * E_ + h * D_ + c4);
      KVs[c4 + 0][tl] = u.x; KVs[c4 + 1][tl] = u.y;
      KVs[c4 + 2][tl] = u.z; KVs[c4 + 3][tl] = u.w;
    }
    __syncthreads();
    #pragma unroll 4
    for (int dd = 0; dd < 16; ++dd) {
      float4 q4 = *(const float4*)(&Qs[ty][dd * 4]);
      float qa[4] = {q4.x, q4.y, q4.z, q4.w};
      #pragma unroll
      for (int k = 0; k < 4; ++k) {
        float4 k4 = *(const float4*)(&KVs[dd * 4 + k][tx * 4]);
        accS[tt][0] += qa[k] * k4.x;
        accS[tt][1] += qa[k] * k4.y;
        accS[tt][2] += qa[k] * k4.z;
        accS[tt][3] += qa[k] * k4.w;
      }
    }
  }

  // ---- row softmax (row = ty, cols spread over 16 tx lanes) ----
  float m = -1e30f;
  #pragma unroll
  for (int tt = 0; tt < 4; ++tt)
    #pragma unroll
    for (int j = 0; j < 4; ++j) {
      int t = tt * 64 + tx * 4 + j;
      float v = (t < S_) ? accS[tt][j] * scale : -1e30f;
      accS[tt][j] = v;
      m = fmaxf(m, v);
    }
  #pragma unroll
  for (int off = 1; off < 16; off <<= 1) m = fmaxf(m, __shfl_xor(m, off));
  float sum = 0.f;
  #pragma unroll
  for (int tt = 0; tt < 4; ++tt)
    #pragma unroll
    for (int j = 0; j < 4; ++j) {
      float pv = __expf(accS[tt][j] - m);
      accS[tt][j] = pv;
      sum += pv;
    }
  #pragma unroll
  for (int off = 1; off < 16; off <<= 1) sum += __shfl_xor(sum, off);
  if (tx == 0) linv[ty] = 1.f / sum;
  #pragma unroll
  for (int tt = 0; tt < 4; ++tt) {
    int t4 = tt * 64 + tx * 4;
    if (t4 < 200)
      *(float4*)(&Ps[ty][t4]) =
          make_float4(accS[tt][0], accS[tt][1], accS[tt][2], accS[tt][3]);
  }

  // ---- PV: KVs = V tile [t][d] ----
  float accO[4] = {0.f, 0.f, 0.f, 0.f};
  #pragma unroll
  for (int tt = 0; tt < 4; ++tt) {
    __syncthreads();   // covers Ps/linv visibility at tt=0
    #pragma unroll
    for (int it = 0; it < 4; ++it) {
      int idx = tid + it * 256;
      int tl = idx >> 4, c4 = (idx & 15) * 4;
      int t = tt * 64 + tl;
      float4 u = make_float4(0.f, 0.f, 0.f, 0.f);
      if (t < S_) u = *(const float4*)(zv + (size_t)(b * S_ + t) * E_ + h * D_ + c4);
      *(float4*)(&KVs[tl][c4]) = u;
    }
    __syncthreads();
    const int tmax = (tt < 3) ? 64 : 8;   // Ps cols < 200 (tail zeros)
    #pragma unroll 8
    for (int tl = 0; tl < tmax; ++tl) {
      float pp = Ps[ty][tt * 64 + tl];
      float4 v4 = *(const float4*)(&KVs[tl][tx * 4]);
      accO[0] += pp * v4.x;
      accO[1] += pp * v4.y;
      accO[2] += pp * v4.z;
      accO[3] += pp * v4.w;
    }
  }

  // epilogue: O = O*inv + V[s]  (identity fold)
  const int s = s0 + ty;
  if (s < S_) {
    float inv = linv[ty];
    float4 vs = *(const float4*)(zv + (size_t)(b * S_ + s) * E_ + h * D_ + tx * 4);
    float4 o;
    o.x = accO[0] * inv + vs.x;
    o.y = accO[1] * inv + vs.y;
    o.z = accO[2] * inv + vs.z;
    o.w = accO[3] * inv + vs.w;
    *(float4*)(obuf + (size_t)(b * S_ + s) * E_ + h * D_ + tx * 4) = o;
  }
}

// ---------------------------------------------------------------------------
// Kernel 5: LayerNorm over last dim (E) per token row. grid(394) block 256.
// ---------------------------------------------------------------------------
__global__ __launch_bounds__(256) void k_lnlast(
    const float* __restrict__ obuf,
    const float* __restrict__ lw, const float* __restrict__ lb,
    float* __restrict__ oln)
{
  const int row = blockIdx.x * 4 + (threadIdx.x >> 6);
  const int lane = threadIdx.x & 63;
  const float* base = obuf + (size_t)row * E_;
  float v[6];
  float s1 = 0.f;
  #pragma unroll
  for (int j = 0; j < 6; ++j) { v[j] = base[lane + 64 * j]; s1 += v[j]; }
  #pragma unroll
  for (int off = 32; off > 0; off >>= 1) s1 += __shfl_xor(s1, off);
  float mean = s1 * (1.f / E_);
  float s2 = 0.f;
  #pragma unroll
  for (int j = 0; j < 6; ++j) { float d = v[j] - mean; s2 += d * d; }
  #pragma unroll
  for (int off = 32; off > 0; off >>= 1) s2 += __shfl_xor(s2, off);
  float rstd = rsqrtf(s2 * (1.f / E_) + 1e-5f);
  float* ob = oln + (size_t)row * E_;
  #pragma unroll
  for (int j = 0; j < 6; ++j) {
    int e = lane + 64 * j;
    ob[e] = (v[j] - mean) * rstd * lw[e] + lb[e];
  }
}

// ---------------------------------------------------------------------------
// Kernel 6: final GEMM  out[n][j] = sum_e oln[n][e]*fcw[j][e] + fcb[j]
// Tile 64j x 32n, thread 4j x 2n.  grid (6, 50) block 256.
// ---------------------------------------------------------------------------
__global__ __launch_bounds__(256) void k_fc(
    const float* __restrict__ oln, const float* __restrict__ fcw,
    const float* __restrict__ fcb, float* __restrict__ out)
{
  const int j0 = blockIdx.x * 64, n0 = blockIdx.y * 32;
  __shared__ float Xs[16][36];   // [e][n]
  __shared__ float Ws[16][68];   // [e][j]
  const int tid = threadIdx.x;
  const int tx = tid & 15, ty = tid >> 4;
  float acc[4][2];
  #pragma unroll
  for (int i = 0; i < 4; ++i) { acc[i][0] = 0.f; acc[i][1] = 0.f; }

  for (int e0 = 0; e0 < E_; e0 += 16) {
    {
      int nl = tid >> 3, e2 = (tid & 7) * 2;
      int n = n0 + nl;
      float2 v = make_float2(0.f, 0.f);
      if (n < N_) v = *(const float2*)(oln + (size_t)n * E_ + e0 + e2);
      Xs[e2 + 0][nl] = v.x; Xs[e2 + 1][nl] = v.y;
      int jl = tid >> 2, c4 = (tid & 3) * 4;
      float4 u = *(const float4*)(fcw + (size_t)(j0 + jl) * E_ + e0 + c4);
      Ws[c4 + 0][jl] = u.x; Ws[c4 + 1][jl] = u.y;
      Ws[c4 + 2][jl] = u.z; Ws[c4 + 3][jl] = u.w;
    }
    __syncthreads();
    #pragma unroll
    for (int cc = 0; cc < 16; ++cc) {
      float2 x2 = *(const float2*)(&Xs[cc][tx * 2]);
      float4 w4 = *(const float4*)(&Ws[cc][ty * 4]);
      float xa[2] = {x2.x, x2.y};
      float wa[4] = {w4.x, w4.y, w4.z, w4.w};
      #pragma unroll
      for (int i = 0; i < 4; ++i) {
        acc[i][0] += wa[i] * xa[0];
        acc[i][1] += wa[i] * xa[1];
      }
    }
    __syncthreads();
  }
  const int jc = j0 + ty * 4;
  float4 bv = *(const float4*)(fcb + jc);
  #pragma unroll
  for (int jn = 0; jn < 2; ++jn) {
    int n = n0 + tx * 2 + jn;
    if (n < N_) {
      float4 o;
      o.x = acc[0][jn] + bv.x;
      o.y = acc[1][jn] + bv.y;
      o.z = acc[2][jn] + bv.z;
      o.w = acc[3][jn] + bv.w;
      *(float4*)(out + (size_t)n * E_ + jc) = o;
    }
  }
}

// ---------------------------------------------------------------------------
extern "C" void kernel_launch(void* const* d_in, const int* in_sizes, int n_in,
                              void* d_out, int out_size, void* d_ws, size_t ws_size,
                              hipStream_t stream)
{
  const float* x   = (const float*)d_in[0];
  const float* wq  = (const float*)d_in[1];
  const float* wk  = (const float*)d_in[2];
  const float* wv  = (const float*)d_in[3];
  const float* qw  = (const float*)d_in[4];
  const float* qb  = (const float*)d_in[5];
  const float* kw  = (const float*)d_in[6];
  const float* kb  = (const float*)d_in[7];
  const float* vw  = (const float*)d_in[8];
  const float* vb  = (const float*)d_in[9];
  const float* ow  = (const float*)d_in[10];
  const float* obp = (const float*)d_in[11];
  const float* fcw = (const float*)d_in[12];
  const float* fcb = (const float*)d_in[13];
  float* out = (float*)d_out;
  float* ws  = (float*)d_ws;

  // ws layout (floats): Y = slots 0..2, Z = slots 3..5.
  // After lnall, Y is dead: obuf = slot 0, oln = slot 1.
  float* Y     = ws;
  float* Z     = ws + 3 * EN;
  float* obuf  = ws + 0 * EN;
  float* oln   = ws + 1 * EN;
  float* part  = ws + 6 * EN;                  // 3*336*2
  float* stats = part + 3 * NBLK_ADD * 2;      // 6

  const float scale = (float)pow(2.0 * D_ * (1.0 - 2.0 / M_PI), -0.5);

  k_adder<<<dim3(NBLK_N, 48, 3), 256, 0, stream>>>(x, wq, wk, wv, Y, part);
  k_stats<<<dim3(3), 256, 0, stream>>>(part, stats);
  k_lnall<<<dim3(NBLK_LN, 3), 256, 0, stream>>>(Y, Z, stats, qw, qb, kw, kb, vw, vb);
  const float* zq = Z;
  const float* zk = Z + EN;
  const float* zv = Z + 2 * EN;
  k_attn<<<dim3(48, 13), 256, 0, stream>>>(zq, zk, zv, obuf, scale);
  k_lnlast<<<dim3(394), 256, 0, stream>>>(obuf, ow, obp, oln);
  k_fc<<<dim3(6, 50), 256, 0, stream>>>(oln, fcw, fcb, out);
}